// Round 1
// baseline (520.339 us; speedup 1.0000x reference)
//
#include <hip/hip_runtime.h>

// VectorQuantizer on MI355X.
// z: [32, 64, 64, 64] fp32 (B, C, H, W), emb: [1024, 64] fp32.
// out: z_q_st [32,64,64,64] fp32 (8388608) then loss (1 float).
//
// Round 0: fp32 baseline. One wave per (b,h) row (64 pixels, lane = w).
// z row held in 64 VGPRs; k-loop reads emb via wave-uniform addresses
// (expect s_load), 4 independent FMA accumulators.

#define NK    1024
#define CDIM  64
#define NELEM 8388608   // 32*64*64*64

__global__ void e2_kernel(const float* __restrict__ emb,
                          float* __restrict__ e2,
                          float* __restrict__ loss_acc) {
    int k = blockIdx.x * blockDim.x + threadIdx.x;
    if (k == 0) loss_acc[0] = 0.0f;   // ws is poisoned 0xAA before every call
    if (k < NK) {
        const float4* row = (const float4*)(emb + k * CDIM);
        float s = 0.0f;
#pragma unroll
        for (int i = 0; i < CDIM / 4; ++i) {
            float4 v = row[i];
            s += v.x * v.x + v.y * v.y + v.z * v.z + v.w * v.w;
        }
        e2[k] = s;
    }
}

__launch_bounds__(64)
__global__ void vq_kernel(const float* __restrict__ z,
                          const float* __restrict__ emb,
                          const float* __restrict__ e2,
                          float* __restrict__ out,
                          float* __restrict__ loss_acc) {
    const int row  = blockIdx.x;        // 0..2047 == b*64 + h
    const int b    = row >> 6;
    const int h    = row & 63;
    const int lane = threadIdx.x;       // w
    // z[b,c,h,w] flat index = b*262144 + c*4096 + h*64 + w
    const int base = b * 262144 + h * 64 + lane;

    float zr[CDIM];
#pragma unroll
    for (int c = 0; c < CDIM; ++c) zr[c] = z[base + c * 4096];

    float best = 3.0e38f;
    int   bk   = 0;
    for (int k = 0; k < NK; ++k) {
        const float* __restrict__ e = emb + k * CDIM;  // wave-uniform -> s_load
        float d0 = 0.f, d1 = 0.f, d2 = 0.f, d3 = 0.f;
#pragma unroll
        for (int c = 0; c < CDIM; c += 4) {
            d0 = fmaf(e[c + 0], zr[c + 0], d0);
            d1 = fmaf(e[c + 1], zr[c + 1], d1);
            d2 = fmaf(e[c + 2], zr[c + 2], d2);
            d3 = fmaf(e[c + 3], zr[c + 3], d3);
        }
        float d = e2[k] - 2.0f * ((d0 + d1) + (d2 + d3));
        if (d < best) { best = d; bk = k; }   // first-min tie-break like argmin
    }

    // Epilogue: gather winning code row (L2-hit scatter), write out
    // transposed (coalesced per c), accumulate squared error.
    const float* __restrict__ eq = emb + bk * CDIM;
    float s = 0.0f;
#pragma unroll
    for (int c = 0; c < CDIM; ++c) {
        float q    = eq[c];
        float zc   = zr[c];
        float diff = q - zc;
        out[base + c * 4096] = zc + diff;   // mirror z + (z_q - z)
        s += diff * diff;
    }

    // wave64 reduction
#pragma unroll
    for (int off = 32; off; off >>= 1) s += __shfl_down(s, off);
    if (lane == 0) atomicAdd(loss_acc, s);
}

__global__ void fin_kernel(const float* __restrict__ loss_acc,
                           float* __restrict__ out_loss) {
    out_loss[0] = 1.5f * loss_acc[0] / (float)NELEM;
}

extern "C" void kernel_launch(void* const* d_in, const int* in_sizes, int n_in,
                              void* d_out, int out_size, void* d_ws, size_t ws_size,
                              hipStream_t stream) {
    const float* z   = (const float*)d_in[0];
    const float* emb = (const float*)d_in[1];
    float* out       = (float*)d_out;
    float* e2        = (float*)d_ws;        // 1024 floats
    float* loss_acc  = e2 + NK;             // 1 float

    e2_kernel<<<dim3(NK / 256), dim3(256), 0, stream>>>(emb, e2, loss_acc);
    vq_kernel<<<dim3(2048), dim3(64), 0, stream>>>(z, emb, e2, out, loss_acc);
    fin_kernel<<<dim3(1), dim3(1), 0, stream>>>(loss_acc, out + NELEM);
}

// Round 2
// 219.030 us; speedup vs baseline: 2.3756x; 2.3756x over previous
//
#include <hip/hip_runtime.h>

// VectorQuantizer on MI355X — Round 2: BF16 MFMA distance matmul.
// z: [32, 64, 64, 64] fp32 (B, C, H, W), emb: [1024, 64] fp32.
// out: z_q_st [32,64,64,64] fp32 (8388608 elems) then loss (1 float).
//
// d = ||e||^2 - 2 z.e  (||z||^2 row-constant, dropped). argmin d ==
// argmax (z.e - 0.5||e||^2). MFMA 16x16x32 bf16: A = emb (rows = codes),
// B = z (cols = pixels); acc init = -0.5||e||^2 (fp32, from fp32 emb).
// One workgroup per (b,h) row: 64 pixels, 4 waves x 16 pixels.
// emb staged to LDS in fragment order, 256-code chunks (4 chunks).
// Epilogue: winning code rows gathered to LDS once, coalesced writes,
// loss from fp32 z and fp32 emb.

#define NK    1024
#define CDIM  64
#define NELEM 8388608

typedef short  sv8  __attribute__((ext_vector_type(8)));
typedef float  fv4  __attribute__((ext_vector_type(4)));
typedef int    iv4  __attribute__((ext_vector_type(4)));

__device__ __forceinline__ unsigned int bf16rne(float f) {
    unsigned int u = __float_as_uint(f);
    return (u + 0x7FFFu + ((u >> 16) & 1u)) >> 16;   // round-to-nearest-even
}

// ---- prep: emb fp32 -> bf16 (ws), e2n[k] = -0.5*||e_k||^2, zero loss acc.
__global__ __launch_bounds__(256) void prep_kernel(
        const float* __restrict__ embf,
        unsigned short* __restrict__ embbf,
        float* __restrict__ e2n,
        float* __restrict__ loss_acc) {
    int t = blockIdx.x * 256 + threadIdx.x;   // 0..4095; code = t>>2, part = t&3
    if (t == 0) loss_acc[0] = 0.0f;
    float s = 0.0f;
    unsigned int pk[8];
#pragma unroll
    for (int j = 0; j < 4; ++j) {
        fv4 v = ((const fv4*)embf)[t * 4 + j];      // floats t*16+j*4 .. +3
        s += v[0]*v[0] + v[1]*v[1] + v[2]*v[2] + v[3]*v[3];
        pk[j*2+0] = bf16rne(v[0]) | (bf16rne(v[1]) << 16);
        pk[j*2+1] = bf16rne(v[2]) | (bf16rne(v[3]) << 16);
    }
    s += __shfl_xor(s, 1);
    s += __shfl_xor(s, 2);
    if ((t & 3) == 0) e2n[t >> 2] = -0.5f * s;
    iv4 o0 = { (int)pk[0], (int)pk[1], (int)pk[2], (int)pk[3] };
    iv4 o1 = { (int)pk[4], (int)pk[5], (int)pk[6], (int)pk[7] };
    ((iv4*)embbf)[t*2+0] = o0;
    ((iv4*)embbf)[t*2+1] = o1;
}

// LDS layout (bytes):
//   0     .. 8192  : z frags bf16, [wv:4][kc:2] regions of 1KB (64 lanes x 16B)
//   8192  .. 40960 : emb chunk frags bf16 [kt:16][kc:2] x 1KB; epilogue reuse:
//                    qlds fp32 [64][65] (16640 B)
//   40960 .. 41984 : e2n chunk, 256 fp32
//   41984 .. 42240 : idx[64] int
#define SMEM_BYTES 42240

__global__ __launch_bounds__(256) void vq_mfma(
        const float* __restrict__ z,
        const float* __restrict__ embf,
        const unsigned short* __restrict__ embbf,
        const float* __restrict__ e2n,
        float* __restrict__ out,
        float* __restrict__ loss_acc) {
    __shared__ char smem[SMEM_BYTES];
    iv4*   zfrag16 = (iv4*)smem;                 // 16B units
    iv4*   efrag16 = (iv4*)(smem + 8192);
    float* e2s     = (float*)(smem + 40960);
    int*   idxs    = (int*)(smem + 41984);
    float* qlds    = (float*)(smem + 8192);      // epilogue reuse

    const int tid = threadIdx.x;
    const int row = blockIdx.x;                  // b*64 + h
    const int b   = row >> 6, h = row & 63;
    const int zbase = b * 262144 + h * 64;       // + c*4096 + w

    // ---- stage z -> bf16 fragments (coalesced dword reads)
    {
        const int u = tid >> 6, n = tid & 63;    // u = channel quad, n = pixel(w)
#pragma unroll
        for (int p = 0; p < 2; ++p) {            // kc (channel 32-chunk)
            unsigned int pk[4];
#pragma unroll
            for (int j = 0; j < 8; j += 2) {
                float f0 = z[zbase + (p*32 + u*8 + j    ) * 4096 + n];
                float f1 = z[zbase + (p*32 + u*8 + j + 1) * 4096 + n];
                pk[j >> 1] = bf16rne(f0) | (bf16rne(f1) << 16);
            }
            iv4 val = { (int)pk[0], (int)pk[1], (int)pk[2], (int)pk[3] };
            // region (wv = n>>4, kc = p), frag-lane = u*16 + (n&15)
            zfrag16[((n >> 4) * 2 + p) * 64 + u * 16 + (n & 15)] = val;
        }
    }
    __syncthreads();

    const int wv   = tid >> 6;
    const int lane = tid & 63;
    const int q    = lane >> 4;                  // quad
    // loop-invariant z B-fragments for this wave (pixels wv*16 + (lane&15))
    sv8 bf0 = ((const sv8*)smem)[(wv * 2 + 0) * 64 + lane];
    sv8 bf1 = ((const sv8*)smem)[(wv * 2 + 1) * 64 + lane];

    float bestv = -3.0e38f;
    int   bestid = 0;

    for (int ch = 0; ch < 4; ++ch) {             // 4 chunks of 256 codes
        __syncthreads();                         // prev chunk's reads done
        {   // stage emb chunk (2048 x 16B units) in fragment order
            const iv4* src = (const iv4*)(embbf + ch * 256 * CDIM);
#pragma unroll
            for (int i = 0; i < 8; ++i) {
                int unit = i * 256 + tid;        // global-contiguous
                int kl = unit >> 3, u = unit & 7;
                iv4 val = src[unit];
                efrag16[(((kl >> 4) * 2 + (u >> 2)) * 64 + (u & 3) * 16 + (kl & 15))] = val;
            }
            e2s[tid] = e2n[ch * 256 + tid];
        }
        __syncthreads();
#pragma unroll
        for (int kt = 0; kt < 16; ++kt) {
            fv4 acc = *(const fv4*)(e2s + kt * 16 + q * 4);
            sv8 a0 = ((const sv8*)efrag16)[(kt * 2 + 0) * 64 + lane];
            sv8 a1 = ((const sv8*)efrag16)[(kt * 2 + 1) * 64 + lane];
            acc = __builtin_amdgcn_mfma_f32_16x16x32_bf16(a0, bf0, acc, 0, 0, 0);
            acc = __builtin_amdgcn_mfma_f32_16x16x32_bf16(a1, bf1, acc, 0, 0, 0);
            const int cb = ch * 256 + kt * 16 + q * 4;
#pragma unroll
            for (int r = 0; r < 4; ++r) {        // ascending code: first max wins
                if (acc[r] > bestv) { bestv = acc[r]; bestid = cb + r; }
            }
        }
    }

    // merge across quads (lanes l, l^16, l^32, l^48 share pixel lane&15)
#pragma unroll
    for (int off = 16; off <= 32; off <<= 1) {
        float ov = __shfl_xor(bestv, off);
        int   oi = __shfl_xor(bestid, off);
        if (ov > bestv || (ov == bestv && oi < bestid)) { bestv = ov; bestid = oi; }
    }
    if (q == 0) idxs[wv * 16 + (lane & 15)] = bestid;
    __syncthreads();

    // ---- gather winning code rows (fp32) into LDS once
    {
        const int n = tid >> 2, part = tid & 3;  // pixel, 16-channel part
        const int id = idxs[n];
#pragma unroll
        for (int j = 0; j < 4; ++j) {
            fv4 v = ((const fv4*)embf)[id * 16 + part * 4 + j];
            const int c = part * 16 + j * 4;
            qlds[n * 65 + c + 0] = v[0];
            qlds[n * 65 + c + 1] = v[1];
            qlds[n * 65 + c + 2] = v[2];
            qlds[n * 65 + c + 3] = v[3];
        }
    }
    __syncthreads();

    // ---- coalesced output + loss (fp32 z re-read, L3-hot)
    float ls = 0.0f;
    {
        const int cc = tid >> 6, w = tid & 63;
#pragma unroll
        for (int it = 0; it < 16; ++it) {
            const int c = it * 4 + cc;
            const float qv = qlds[w * 65 + c];
            const float zv = z[zbase + c * 4096 + w];
            const float d  = qv - zv;
            out[zbase + c * 4096 + w] = qv;      // z + (z_q - z) == z_q exactly
            ls += d * d;
        }
    }
#pragma unroll
    for (int off = 32; off; off >>= 1) ls += __shfl_down(ls, off);
    if (lane == 0) atomicAdd(loss_acc, ls);
}

__global__ void fin_kernel(const float* __restrict__ loss_acc,
                           float* __restrict__ out_loss) {
    out_loss[0] = 1.5f * loss_acc[0] / (float)NELEM;
}

extern "C" void kernel_launch(void* const* d_in, const int* in_sizes, int n_in,
                              void* d_out, int out_size, void* d_ws, size_t ws_size,
                              hipStream_t stream) {
    const float* z    = (const float*)d_in[0];
    const float* embf = (const float*)d_in[1];
    float* out        = (float*)d_out;

    unsigned short* embbf = (unsigned short*)d_ws;          // 1024*64 bf16 = 128 KB
    float* e2n            = (float*)((char*)d_ws + 131072); // 1024 f32
    float* loss_acc       = e2n + NK;                       // 1 f32

    prep_kernel<<<dim3(16), dim3(256), 0, stream>>>(embf, embbf, e2n, loss_acc);
    vq_mfma<<<dim3(2048), dim3(256), 0, stream>>>(z, embf, embbf, e2n, out, loss_acc);
    fin_kernel<<<dim3(1), dim3(1), 0, stream>>>(loss_acc, out + NELEM);
}

// Round 3
// 129.956 us; speedup vs baseline: 4.0040x; 1.6854x over previous
//
#include <hip/hip_runtime.h>

// VectorQuantizer on MI355X — Round 3: codebook-in-registers MFMA.
// z: [32, 64, 64, 64] fp32 (B,C,H,W), emb: [1024, 64] fp32.
// out: z_q [32,64,64,64] fp32 (8388608) then loss (1 float).
//
// argmin_k ||z-e_k||^2 == argmax_k (z.e_k - 0.5||e_k||^2)  (||z||^2 dropped).
// Block = 1024 threads = 16 waves; wave wv owns codes [wv*64, wv*64+64) as
// 8 loop-invariant bf16 A-frags (converted in-kernel from fp32 emb) + fp32
// -0.5||e||^2 accumulator-init regs. 256 pixels/block staged once to LDS in
// B-frag order (staging writes conflict-free: consecutive 8 lanes hit
// distinct addr16%8). Main loop: NO syncthreads — 16 pixel-tiles x
// (2 ds_read_b128 + 8 MFMA + argmax bookkeeping). Cross-wave merge via
// padded (stride-17) LDS candidate buffer; epilogue gathers fp32 code rows,
// writes out, accumulates loss to per-block partials in ws (fin sums).

#define NELEM 8388608
#define NBLK  512     // 256 pixels per block

typedef short  sv8 __attribute__((ext_vector_type(8)));
typedef float  fv4 __attribute__((ext_vector_type(4)));
typedef int    iv4 __attribute__((ext_vector_type(4)));

__device__ __forceinline__ unsigned int bf16rne(float f) {
    unsigned int u = __float_as_uint(f);
    return (u + 0x7FFFu + ((u >> 16) & 1u)) >> 16;
}

__global__ __launch_bounds__(1024, 4) void vq_kernel(
        const float* __restrict__ z,
        const float* __restrict__ embf,
        float* __restrict__ out,
        float* __restrict__ blksum) {
    __shared__ iv4            zfrag[32 * 64];   // 32 KB: [pt*2+kc][fraglane]
    __shared__ float          vbuf[256 * 17];   // 17.4 KB: [pixel][wv] best val
    __shared__ unsigned short ibuf[256 * 17];   // 8.7 KB: [pixel][wv] local id
    __shared__ int            idxf[256];        // final code per pixel
    __shared__ float          wred[16];

    const int tid   = threadIdx.x;
    const int blk   = blockIdx.x;
    const int batch = blk >> 4;
    const int hw0   = (blk & 15) << 8;          // 256 pixels within 64x64 plane
    const int zb    = batch * 262144;           // + c*4096 + (hw0 + p)

    // ---- stage z -> bf16 B-fragments (2 units of 16B per thread)
#pragma unroll
    for (int m = 0; m < 2; ++m) {
        const int R = m * 16 + (tid >> 6);      // pt*2 + kc
        const int l = tid & 63;
        const int q = l >> 4, s = l & 15;
        const int col = hw0 + (R >> 1) * 16 + s;
        const int cb  = (R & 1) * 32 + q * 8;
        unsigned int pk[4];
#pragma unroll
        for (int jj = 0; jj < 4; ++jj) {
            float f0 = z[zb + (cb + jj * 2 + 0) * 4096 + col];
            float f1 = z[zb + (cb + jj * 2 + 1) * 4096 + col];
            pk[jj] = bf16rne(f0) | (bf16rne(f1) << 16);
        }
        iv4 v = { (int)pk[0], (int)pk[1], (int)pk[2], (int)pk[3] };
        zfrag[R * 64 + l] = v;                  // lane-contiguous: conflict-free
    }

    // ---- build A-frags (bf16) + acc-init (-0.5||e||^2, fp32) in registers
    const int wv   = tid >> 6;
    const int lane = tid & 63;
    const int q    = lane >> 4;
    const int mcol = lane & 15;

    sv8 afr[4][2];
    fv4 einit[4];
#pragma unroll
    for (int kt = 0; kt < 4; ++kt) {
        const int code = wv * 64 + kt * 16 + mcol;
        float s2 = 0.0f;
#pragma unroll
        for (int kc = 0; kc < 2; ++kc) {
            fv4 u0 = ((const fv4*)embf)[code * 16 + kc * 8 + q * 2 + 0];
            fv4 u1 = ((const fv4*)embf)[code * 16 + kc * 8 + q * 2 + 1];
            s2 += u0[0]*u0[0] + u0[1]*u0[1] + u0[2]*u0[2] + u0[3]*u0[3]
                + u1[0]*u1[0] + u1[1]*u1[1] + u1[2]*u1[2] + u1[3]*u1[3];
            unsigned int p0 = bf16rne(u0[0]) | (bf16rne(u0[1]) << 16);
            unsigned int p1 = bf16rne(u0[2]) | (bf16rne(u0[3]) << 16);
            unsigned int p2 = bf16rne(u1[0]) | (bf16rne(u1[1]) << 16);
            unsigned int p3 = bf16rne(u1[2]) | (bf16rne(u1[3]) << 16);
            iv4 pv = { (int)p0, (int)p1, (int)p2, (int)p3 };
            afr[kt][kc] = *(sv8*)&pv;
        }
        s2 += __shfl_xor(s2, 16);
        s2 += __shfl_xor(s2, 32);               // full ||e_code||^2, all lanes
#pragma unroll
        for (int r = 0; r < 4; ++r)             // rearrange to C/D row layout
            einit[kt][r] = -0.5f * __shfl(s2, (lane & 48) | (q * 4 + r));
    }
    __syncthreads();                            // staging visible

    // ---- main loop: 16 pixel-tiles, no syncs
#pragma unroll 4
    for (int pt = 0; pt < 16; ++pt) {
        sv8 b0 = ((const sv8*)zfrag)[(pt * 2 + 0) * 64 + lane];
        sv8 b1 = ((const sv8*)zfrag)[(pt * 2 + 1) * 64 + lane];
        float bestv = -3.0e38f;
        int   bid   = 0;
#pragma unroll
        for (int kt = 0; kt < 4; ++kt) {
            fv4 acc = einit[kt];
            acc = __builtin_amdgcn_mfma_f32_16x16x32_bf16(afr[kt][0], b0, acc, 0, 0, 0);
            acc = __builtin_amdgcn_mfma_f32_16x16x32_bf16(afr[kt][1], b1, acc, 0, 0, 0);
#pragma unroll
            for (int r = 0; r < 4; ++r) {       // ascending local code
                const int id = kt * 16 + q * 4 + r;
                if (acc[r] > bestv) { bestv = acc[r]; bid = id; }
            }
        }
        // merge across the 4 quads (same pixel column)
#pragma unroll
        for (int off = 16; off <= 32; off <<= 1) {
            float ov = __shfl_xor(bestv, off);
            int   oi = __shfl_xor(bid, off);
            if (ov > bestv || (ov == bestv && oi < bid)) { bestv = ov; bid = oi; }
        }
        if (lane < 16) {
            vbuf[(pt * 16 + lane) * 17 + wv] = bestv;
            ibuf[(pt * 16 + lane) * 17 + wv] = (unsigned short)bid;
        }
    }
    __syncthreads();

    // ---- per-pixel cross-wave argmax (first max = lowest code on ties)
    if (tid < 256) {
        float bv = vbuf[tid * 17];
        int   bc = ibuf[tid * 17];
#pragma unroll
        for (int w2 = 1; w2 < 16; ++w2) {
            float v = vbuf[tid * 17 + w2];
            if (v > bv) { bv = v; bc = w2 * 64 + ibuf[tid * 17 + w2]; }
        }
        idxf[tid] = bc;
    }
    __syncthreads();

    // ---- epilogue: gather fp32 code row, write out, loss
    const int p    = tid >> 2;                  // pixel in block
    const int part = tid & 3;                   // 16-channel slice
    const int id   = idxf[p];
    const int gp   = hw0 + p;
    float ls = 0.0f;
#pragma unroll
    for (int j = 0; j < 4; ++j) {
        fv4 e = ((const fv4*)embf)[id * 16 + part * 4 + j];
#pragma unroll
        for (int ee = 0; ee < 4; ++ee) {
            const int c = part * 16 + j * 4 + ee;
            const int a = zb + c * 4096 + gp;
            float d = e[ee] - z[a];
            out[a] = e[ee];                     // z + (z_q - z) == z_q
            ls += d * d;
        }
    }
#pragma unroll
    for (int off = 32; off; off >>= 1) ls += __shfl_down(ls, off);
    if (lane == 0) wred[wv] = ls;
    __syncthreads();
    if (tid == 0) {
        float s = 0.0f;
#pragma unroll
        for (int i = 0; i < 16; ++i) s += wred[i];
        blksum[blk] = s;
    }
}

__global__ void fin_kernel(const float* __restrict__ blksum,
                           float* __restrict__ out_loss) {
    __shared__ float w[8];
    const int t = threadIdx.x;
    float s = blksum[t];
#pragma unroll
    for (int off = 32; off; off >>= 1) s += __shfl_down(s, off);
    if ((t & 63) == 0) w[t >> 6] = s;
    __syncthreads();
    if (t == 0) {
        float tot = 0.0f;
#pragma unroll
        for (int i = 0; i < 8; ++i) tot += w[i];
        out_loss[0] = 1.5f * tot / (float)NELEM;
    }
}

extern "C" void kernel_launch(void* const* d_in, const int* in_sizes, int n_in,
                              void* d_out, int out_size, void* d_ws, size_t ws_size,
                              hipStream_t stream) {
    const float* z    = (const float*)d_in[0];
    const float* embf = (const float*)d_in[1];
    float* out        = (float*)d_out;
    float* blksum     = (float*)d_ws;           // 512 floats, all written

    vq_kernel<<<dim3(NBLK), dim3(1024), 0, stream>>>(z, embf, out, blksum);
    fin_kernel<<<dim3(1), dim3(512), 0, stream>>>(blksum, out + NELEM);
}